// Round 5
// baseline (55.225 us; speedup 1.0000x reference)
//
#include <hip/hip_runtime.h>
#include <hip/hip_bf16.h>

#define A_N 8
#define C_N 256
#define H_N 80
#define W_N 108
#define P_N (H_N * W_N)      // 8640
#define O_N 7
#define MH 256               // mask H
#define MW 256               // mask W
#define OUT_HW 256

#define PXT  32              // pixels per conv block
#define NCG  16              // channel groups
#define CPG  16              // channels per group
#define BPA  270             // conv blocks per agent (P_N/PXT)
#define MROWS 12             // max staged mask rows per block

// padded weight-table offset: +4 floats every 16 channels -> group stride
// 16*8+4=132 words == 4 mod 32 banks (conflict-free b128 broadcast)
#define W8OFF(c) ((c) * 8 + ((c) >> 4) * 4)
#define W8SIZE   (C_N * 8 + NCG * 4)   // 2112 floats

__device__ __forceinline__ float sigmoidf_(float zv) {
    return 1.0f / (1.0f + __expf(-zv));
}

// ---------------------------------------------------------------------------
// Fused conv: z[a,o,p] = sum_c w[o,c]*x[a,c,p] + wsum[o]*cm[a,p]
//             ssolo    = sigmoid(z + b[o])
// cm computed in-block from LDS-staged mask rows (antialias triangle kernel,
// jax.image.resize semantics). Grid 8*270=2160 blocks x 256 thr.
// ---------------------------------------------------------------------------
__launch_bounds__(256)
__global__ void k_conv(const float* __restrict__ x, const float* __restrict__ masks,
                       const float* __restrict__ w, const float* __restrict__ b,
                       float* __restrict__ z, float* __restrict__ ssolo)
{
    __shared__ float s_w[W8SIZE];                 // [c][o] padded
    __shared__ float s_acc[NCG][CPG][15];         // row stride 15: odd -> no conflicts
    __shared__ float s_mask[MROWS * MW];
    __shared__ float s_cm[PXT];
    __shared__ float s_wsum[O_N];

    const int tid = threadIdx.x;
    const int a   = blockIdx.x / BPA;
    const int p0  = (blockIdx.x - a * BPA) * PXT;

    // ---- stage transposed+padded weights ----
    #pragma unroll
    for (int k = 0; k < 8; ++k) {
        int idx = k * 256 + tid;                  // = c*8 + o
        int c = idx >> 3, o = idx & 7;
        s_w[W8OFF(c) + o] = (o < O_N) ? w[o * C_N + c] : 0.0f;
    }
    if (tid < O_N) {
        const float4* wr = reinterpret_cast<const float4*>(w + tid * C_N);
        float s = 0.0f;
        #pragma unroll 4
        for (int c4 = 0; c4 < C_N / 4; ++c4) { float4 v = wr[c4]; s += v.x + v.y + v.z + v.w; }
        s_wsum[tid] = s;
    }

    // ---- stage mask rows needed by this tile's 32 px (<=12 rows) ----
    const float ksy = 256.0f / 80.0f;
    const float ksx = 256.0f / 108.0f;
    const float rky = 0.3125f;                    // 80/256 exact
    const float rkx = 0.421875f;                  // 108/256 exact

    const int oy0 = p0 / W_N;
    const int oy1 = (p0 + PXT - 1) / W_N;
    const int iyLo = max(0, (int)ceilf(((float)oy0 + 0.5f) * ksy - 0.5f - ksy));
    const int iyHi = min(MH - 1, (int)floorf(((float)oy1 + 0.5f) * ksy - 0.5f + ksy));
    const int nq = (iyHi - iyLo + 1) * (MW / 4);  // float4 count, <= 768
    const float4* msrc = reinterpret_cast<const float4*>(masks + ((size_t)a * MH + iyLo) * MW);
    float4* mdst = reinterpret_cast<float4*>(s_mask);
    for (int i = tid; i < nq; i += 256) mdst[i] = msrc[i];
    __syncthreads();

    // ---- channel-split conv: 16 px-pairs x 16 channel-groups ----
    const int pr = tid & 15;                      // pixel pair
    const int cg = tid >> 4;                      // channel group
    const int px0 = p0 + pr * 2;

    float a0[O_N], a1[O_N];
    #pragma unroll
    for (int o = 0; o < O_N; ++o) { a0[o] = 0.0f; a1[o] = 0.0f; }

    const float* xp = x + (size_t)(a * C_N + cg * CPG) * P_N + px0;
    #pragma unroll 8
    for (int cc = 0; cc < CPG; ++cc) {
        float2 v = *reinterpret_cast<const float2*>(xp + (size_t)cc * P_N);
        const int c = cg * CPG + cc;
        float4 wA = *reinterpret_cast<const float4*>(&s_w[W8OFF(c)]);
        float4 wB = *reinterpret_cast<const float4*>(&s_w[W8OFF(c) + 4]);
        a0[0] = fmaf(wA.x, v.x, a0[0]); a1[0] = fmaf(wA.x, v.y, a1[0]);
        a0[1] = fmaf(wA.y, v.x, a0[1]); a1[1] = fmaf(wA.y, v.y, a1[1]);
        a0[2] = fmaf(wA.z, v.x, a0[2]); a1[2] = fmaf(wA.z, v.y, a1[2]);
        a0[3] = fmaf(wA.w, v.x, a0[3]); a1[3] = fmaf(wA.w, v.y, a1[3]);
        a0[4] = fmaf(wB.x, v.x, a0[4]); a1[4] = fmaf(wB.x, v.y, a1[4]);
        a0[5] = fmaf(wB.y, v.x, a0[5]); a1[5] = fmaf(wB.y, v.y, a1[5]);
        a0[6] = fmaf(wB.z, v.x, a0[6]); a1[6] = fmaf(wB.z, v.y, a1[6]);
    }

    #pragma unroll
    for (int o = 0; o < O_N; ++o) {
        s_acc[cg][pr][2 * o]     = a0[o];
        s_acc[cg][pr][2 * o + 1] = a1[o];
    }

    // ---- cm from LDS-staged mask rows (lanes 0..31, one per px) ----
    if (tid < PXT) {
        const int ppx = p0 + tid;
        const int oy = ppx / W_N, ox = ppx - oy * W_N;
        const float sfy = ((float)oy + 0.5f) * ksy - 0.5f;
        const float sfx = ((float)ox + 0.5f) * ksx - 0.5f;
        const int jy0 = max(0, (int)ceilf(sfy - ksy));
        const int jy1 = min(MH - 1, (int)floorf(sfy + ksy));
        const int jx0 = max(0, (int)ceilf(sfx - ksx));
        const int jx1 = min(MW - 1, (int)floorf(sfx + ksx));
        float wys = 0.0f, wxs = 0.0f, acc = 0.0f;
        for (int ix = jx0; ix <= jx1; ++ix)
            wxs += fmaxf(0.0f, 1.0f - fabsf(sfx - (float)ix) * rkx);
        for (int iy = jy0; iy <= jy1; ++iy) {
            float wyv = fmaxf(0.0f, 1.0f - fabsf(sfy - (float)iy) * rky);
            wys += wyv;
            const float* row = s_mask + (iy - iyLo) * MW;
            float racc = 0.0f;
            for (int ix = jx0; ix <= jx1; ++ix)
                racc += fmaxf(0.0f, 1.0f - fabsf(sfx - (float)ix) * rkx) * row[ix];
            acc += wyv * racc;
        }
        s_cm[tid] = acc / (wys * wxs);
    }
    __syncthreads();

    // ---- reduce 16 partials: 112 threads = 7 outputs x 16 pairs ----
    if (tid < O_N * CPG) {
        const int o   = tid >> 4;
        const int pr2 = tid & 15;
        float s0 = 0.0f, s1 = 0.0f;
        #pragma unroll
        for (int g = 0; g < NCG; ++g) {
            s0 += s_acc[g][pr2][2 * o];
            s1 += s_acc[g][pr2][2 * o + 1];
        }
        const float wsum = s_wsum[o];
        const float z0 = s0 + wsum * s_cm[pr2 * 2];
        const float z1 = s1 + wsum * s_cm[pr2 * 2 + 1];
        const float bo = b[o];
        const size_t ob = (size_t)(a * O_N + o) * P_N + p0 + pr2 * 2;
        *reinterpret_cast<float2*>(z + ob)     = make_float2(z0, z1);
        *reinterpret_cast<float2*>(ssolo + ob) =
            make_float2(sigmoidf_(z0 + bo), sigmoidf_(z1 + bo));
    }
}

// ---------------------------------------------------------------------------
// Aggregation: per ego i, pixel p: saggr = sigmoid(b + sum_j adj[i,j]!=0 ?
//              zero-padded-bilinear(z[j], rel[i,j] @ [u,v,1]) : 0)
// z planes total 1.9 MB — L2-resident gathers. 1080 blocks x 64 (4+ waves/CU).
// ---------------------------------------------------------------------------
__launch_bounds__(64)
__global__ void k_aggr(const float* __restrict__ z, const float* __restrict__ rel,
                       const int* __restrict__ adj, const float* __restrict__ b,
                       float* __restrict__ saggr)
{
    const int i = blockIdx.x / 135;                       // agent (135 blocks/agent)
    const int p = (blockIdx.x - i * 135) * 64 + threadIdx.x;
    const int vy = p / W_N, ux = p - vy * W_N;
    const float fu = (float)ux, fv = (float)vy;

    float acc[O_N];
    #pragma unroll
    for (int o = 0; o < O_N; ++o) acc[o] = b[o];

    for (int j = 0; j < A_N; ++j) {
        if (adj[i * A_N + j] == 0) continue;
        const float* M = rel + (i * A_N + j) * 6;
        float sx = M[0] * fu + M[1] * fv + M[2];
        float sy = M[3] * fu + M[4] * fv + M[5];
        if (!(sx > -1.0f && sx < (float)W_N && sy > -1.0f && sy < (float)H_N)) continue;
        float x0f = floorf(sx), y0f = floorf(sy);
        float wx = sx - x0f, wy = sy - y0f;
        int x0 = (int)x0f, y0 = (int)y0f;
        int x1 = x0 + 1,  y1 = y0 + 1;
        float w00 = (1.0f - wy) * (1.0f - wx), w01 = (1.0f - wy) * wx;
        float w10 = wy * (1.0f - wx),          w11 = wy * wx;
        if (x0 < 0)    { w00 = 0.0f; w10 = 0.0f; x0 = 0; }
        if (x1 >= W_N) { w01 = 0.0f; w11 = 0.0f; x1 = W_N - 1; }
        if (y0 < 0)    { w00 = 0.0f; w01 = 0.0f; y0 = 0; }
        if (y1 >= H_N) { w10 = 0.0f; w11 = 0.0f; y1 = H_N - 1; }
        const int i00 = y0 * W_N + x0, i01 = y0 * W_N + x1;
        const int i10 = y1 * W_N + x0, i11 = y1 * W_N + x1;
        const float* zj = z + j * O_N * P_N;
        #pragma unroll
        for (int o = 0; o < O_N; ++o) {
            const float* zp = zj + o * P_N;
            acc[o] += w00 * zp[i00] + w01 * zp[i01] + w10 * zp[i10] + w11 * zp[i11];
        }
    }
    const int ob = i * O_N * P_N + p;
    #pragma unroll
    for (int o = 0; o < O_N; ++o) saggr[ob + o * P_N] = sigmoidf_(acc[o]);
}

// ---------------------------------------------------------------------------
// Upsample: align_corners=True bilinear 80x108 -> 256x256, f32 out.
// 4 px/thread -> float4 stores; 7168 blocks x 256 exact.
// Output layout: [solo(8,7,256,256), aggr(8,7,256,256)] flat f32.
// ---------------------------------------------------------------------------
__launch_bounds__(256)
__global__ void k_upsample(const float* __restrict__ ssolo, const float* __restrict__ saggr,
                           float* __restrict__ out)
{
    const int idx = blockIdx.x * 256 + threadIdx.x;   // quad index
    int k = idx;
    const int oxq = k & 63;   k >>= 6;
    const int oy  = k & 255;  k >>= 8;
    const int o   = k % O_N;  k /= O_N;
    const int a   = k & 7;    k >>= 3;
    const int t   = k;        // 0 = solo, 1 = aggr

    const float* src = (t == 0 ? ssolo : saggr) + (a * O_N + o) * P_N;
    float syf = (float)oy * (79.0f / 255.0f);
    int y0 = (int)syf; y0 = min(y0, H_N - 2);
    float wy = syf - (float)y0;
    const float* r0 = src + y0 * W_N;
    const float* r1 = r0 + W_N;

    float res[4];
    #pragma unroll
    for (int q = 0; q < 4; ++q) {
        int ox = oxq * 4 + q;
        float sxf = (float)ox * (107.0f / 255.0f);
        int x0 = (int)sxf; x0 = min(x0, W_N - 2);
        float wx = sxf - (float)x0;
        float c0 = r0[x0]     * (1.0f - wy) + r1[x0]     * wy;
        float c1 = r0[x0 + 1] * (1.0f - wy) + r1[x0 + 1] * wy;
        res[q] = c0 * (1.0f - wx) + c1 * wx;
    }
    *reinterpret_cast<float4*>(out + (size_t)idx * 4) =
        make_float4(res[0], res[1], res[2], res[3]);
}

// ---------------------------------------------------------------------------
extern "C" void kernel_launch(void* const* d_in, const int* in_sizes, int n_in,
                              void* d_out, int out_size, void* d_ws, size_t ws_size,
                              hipStream_t stream)
{
    (void)in_sizes; (void)n_in; (void)out_size; (void)ws_size;
    const float* x    = (const float*)d_in[0];
    const float* rel  = (const float*)d_in[1];
    const int*   adj  = (const int*)d_in[2];
    const float* cmsk = (const float*)d_in[3];
    const float* wcls = (const float*)d_in[4];
    const float* bcls = (const float*)d_in[5];
    float* out = (float*)d_out;   // reference output dtype is float32

    float* ws    = (float*)d_ws;
    float* z     = ws;                          // 8*7*8640 = 483,840 f32
    float* ssolo = z     + A_N * O_N * P_N;     // 483,840 f32
    float* saggr = ssolo + A_N * O_N * P_N;     // 483,840 f32  (~5.8 MB total)

    k_conv<<<A_N * BPA, 256, 0, stream>>>(x, cmsk, wcls, bcls, z, ssolo);
    k_aggr<<<1080, 64, 0, stream>>>(z, rel, adj, bcls, saggr);
    k_upsample<<<7168, 256, 0, stream>>>(ssolo, saggr, out);
}

// Round 6
// 48.133 us; speedup vs baseline: 1.1473x; 1.1473x over previous
//
#include <hip/hip_runtime.h>
#include <hip/hip_bf16.h>

#define A_N 8
#define C_N 256
#define H_N 80
#define W_N 108
#define P_N (H_N * W_N)      // 8640
#define O_N 7
#define MH 256               // mask H
#define MW 256               // mask W
#define OUT_HW 256

#define TILE   512           // px per conv block (2KB contiguous per channel read)
#define NTIL   17            // ceil(P_N/TILE)
#define GSP    2             // channel split
#define CPG2   (C_N / GSP)   // 128 channels per half

__device__ __forceinline__ float sigmoidf_(float zv) {
    return 1.0f / (1.0f + __expf(-zv));
}

// ---------------------------------------------------------------------------
// Split-K conv, px-contiguous streaming.
// Grid: 8 agents x 17 tiles x 2 ch-halves = 272 blocks x 512 thr, 1 px/thread.
// Per channel iteration the block reads 512 consecutive floats (2KB DRAM run).
//   part[g][a][o][p] = sum_{c in half g} w[o,c] * x[a,c,p]
// ---------------------------------------------------------------------------
__launch_bounds__(512)
__global__ void k_convp(const float* __restrict__ x, const float* __restrict__ w,
                        float* __restrict__ part)
{
    const int bi   = blockIdx.x;
    const int g    = bi & 1;
    const int t2   = bi >> 1;
    const int tile = t2 % NTIL;
    const int a    = t2 / NTIL;

    const int px  = tile * TILE + threadIdx.x;
    const int pxc = min(px, P_N - 1);            // clamp loads; guard stores

    float acc[O_N];
    #pragma unroll
    for (int o = 0; o < O_N; ++o) acc[o] = 0.0f;

    const float* xp = x + ((size_t)a * C_N + g * CPG2) * P_N + pxc;
    const float* wp = w + g * CPG2;

    #pragma unroll 8
    for (int cc = 0; cc < CPG2; ++cc) {
        float v = xp[(size_t)cc * P_N];
        #pragma unroll
        for (int o = 0; o < O_N; ++o)
            acc[o] = fmaf(wp[o * C_N + cc], v, acc[o]);   // uniform -> scalar load
    }

    if (px < P_N) {
        const size_t pb = ((size_t)(g * A_N + a) * O_N) * P_N + px;
        #pragma unroll
        for (int o = 0; o < O_N; ++o)
            part[pb + (size_t)o * P_N] = acc[o];
    }
}

// ---------------------------------------------------------------------------
// Finalize: z = part0 + part1 + wsum*cm ; ssolo = sigmoid(z + b)
// cm = antialias bilinear resize (jax.image.resize) of car_masks, computed
// inline per pixel from L2-resident masks. Grid 270 x 256 (exact).
// ---------------------------------------------------------------------------
__launch_bounds__(256)
__global__ void k_finalize(const float* __restrict__ part, const float* __restrict__ masks,
                           const float* __restrict__ w, const float* __restrict__ b,
                           float* __restrict__ z, float* __restrict__ ssolo)
{
    __shared__ float s_wsum[O_N];
    if (threadIdx.x < O_N) {
        const float4* wr = reinterpret_cast<const float4*>(w + threadIdx.x * C_N);
        float s = 0.0f;
        #pragma unroll 4
        for (int c4 = 0; c4 < C_N / 4; ++c4) { float4 v = wr[c4]; s += v.x + v.y + v.z + v.w; }
        s_wsum[threadIdx.x] = s;
    }
    __syncthreads();

    const int idx = blockIdx.x * 256 + threadIdx.x;   // < 69120 exact
    const int a = idx / P_N, p = idx - a * P_N;
    const int oy = p / W_N, ox = p - oy * W_N;

    // ---- antialias triangle-kernel resize ----
    const float ksy = 256.0f / 80.0f;
    const float ksx = 256.0f / 108.0f;
    const float rky = 0.3125f;           // 80/256 exact
    const float rkx = 0.421875f;         // 108/256 exact

    float sfy = ((float)oy + 0.5f) * ksy - 0.5f;
    float sfx = ((float)ox + 0.5f) * ksx - 0.5f;
    int iy0 = max(0, (int)ceilf(sfy - ksy));
    int iy1 = min(MH - 1, (int)floorf(sfy + ksy));
    int ix0 = max(0, (int)ceilf(sfx - ksx));
    int ix1 = min(MW - 1, (int)floorf(sfx + ksx));

    float wys = 0.0f, wxs = 0.0f;
    for (int iy = iy0; iy <= iy1; ++iy)
        wys += fmaxf(0.0f, 1.0f - fabsf(sfy - (float)iy) * rky);
    for (int ix = ix0; ix <= ix1; ++ix)
        wxs += fmaxf(0.0f, 1.0f - fabsf(sfx - (float)ix) * rkx);

    const float* mp = masks + a * (MH * MW);
    float acc = 0.0f;
    for (int iy = iy0; iy <= iy1; ++iy) {
        float wyv = fmaxf(0.0f, 1.0f - fabsf(sfy - (float)iy) * rky);
        const float* row = mp + iy * MW;
        float racc = 0.0f;
        for (int ix = ix0; ix <= ix1; ++ix)
            racc += fmaxf(0.0f, 1.0f - fabsf(sfx - (float)ix) * rkx) * row[ix];
        acc += wyv * racc;
    }
    const float cmv = acc / (wys * wxs);

    // ---- combine partials ----
    const size_t p0 = ((size_t)(0 * A_N + a) * O_N) * P_N + p;
    const size_t p1 = ((size_t)(1 * A_N + a) * O_N) * P_N + p;
    const size_t zb = ((size_t)a * O_N) * P_N + p;
    #pragma unroll
    for (int o = 0; o < O_N; ++o) {
        float zv = part[p0 + (size_t)o * P_N] + part[p1 + (size_t)o * P_N]
                 + s_wsum[o] * cmv;
        z[zb + (size_t)o * P_N]     = zv;
        ssolo[zb + (size_t)o * P_N] = sigmoidf_(zv + b[o]);
    }
}

// ---------------------------------------------------------------------------
// Aggregation: per ego i, pixel p: saggr = sigmoid(b + sum_j adj[i,j]!=0 ?
//              zero-padded-bilinear(z[j], rel[i,j] @ [u,v,1]) : 0)
// z planes total 1.9 MB — L2-resident gathers. 1080 blocks x 64.
// ---------------------------------------------------------------------------
__launch_bounds__(64)
__global__ void k_aggr(const float* __restrict__ z, const float* __restrict__ rel,
                       const int* __restrict__ adj, const float* __restrict__ b,
                       float* __restrict__ saggr)
{
    const int i = blockIdx.x / 135;
    const int p = (blockIdx.x - i * 135) * 64 + threadIdx.x;
    const int vy = p / W_N, ux = p - vy * W_N;
    const float fu = (float)ux, fv = (float)vy;

    float acc[O_N];
    #pragma unroll
    for (int o = 0; o < O_N; ++o) acc[o] = b[o];

    for (int j = 0; j < A_N; ++j) {
        if (adj[i * A_N + j] == 0) continue;
        const float* M = rel + (i * A_N + j) * 6;
        float sx = M[0] * fu + M[1] * fv + M[2];
        float sy = M[3] * fu + M[4] * fv + M[5];
        if (!(sx > -1.0f && sx < (float)W_N && sy > -1.0f && sy < (float)H_N)) continue;
        float x0f = floorf(sx), y0f = floorf(sy);
        float wx = sx - x0f, wy = sy - y0f;
        int x0 = (int)x0f, y0 = (int)y0f;
        int x1 = x0 + 1,  y1 = y0 + 1;
        float w00 = (1.0f - wy) * (1.0f - wx), w01 = (1.0f - wy) * wx;
        float w10 = wy * (1.0f - wx),          w11 = wy * wx;
        if (x0 < 0)    { w00 = 0.0f; w10 = 0.0f; x0 = 0; }
        if (x1 >= W_N) { w01 = 0.0f; w11 = 0.0f; x1 = W_N - 1; }
        if (y0 < 0)    { w00 = 0.0f; w01 = 0.0f; y0 = 0; }
        if (y1 >= H_N) { w10 = 0.0f; w11 = 0.0f; y1 = H_N - 1; }
        const int i00 = y0 * W_N + x0, i01 = y0 * W_N + x1;
        const int i10 = y1 * W_N + x0, i11 = y1 * W_N + x1;
        const float* zj = z + j * O_N * P_N;
        #pragma unroll
        for (int o = 0; o < O_N; ++o) {
            const float* zp = zj + o * P_N;
            acc[o] += w00 * zp[i00] + w01 * zp[i01] + w10 * zp[i10] + w11 * zp[i11];
        }
    }
    const int ob = i * O_N * P_N + p;
    #pragma unroll
    for (int o = 0; o < O_N; ++o) saggr[ob + o * P_N] = sigmoidf_(acc[o]);
}

// ---------------------------------------------------------------------------
// Upsample: align_corners=True bilinear 80x108 -> 256x256, f32 out.
// 4 px/thread -> float4 stores; 7168 blocks x 256 exact.
// Output layout: [solo(8,7,256,256), aggr(8,7,256,256)] flat f32.
// ---------------------------------------------------------------------------
__launch_bounds__(256)
__global__ void k_upsample(const float* __restrict__ ssolo, const float* __restrict__ saggr,
                           float* __restrict__ out)
{
    const int idx = blockIdx.x * 256 + threadIdx.x;   // quad index
    int k = idx;
    const int oxq = k & 63;   k >>= 6;
    const int oy  = k & 255;  k >>= 8;
    const int o   = k % O_N;  k /= O_N;
    const int a   = k & 7;    k >>= 3;
    const int t   = k;        // 0 = solo, 1 = aggr

    const float* src = (t == 0 ? ssolo : saggr) + (a * O_N + o) * P_N;
    float syf = (float)oy * (79.0f / 255.0f);
    int y0 = (int)syf; y0 = min(y0, H_N - 2);
    float wy = syf - (float)y0;
    const float* r0 = src + y0 * W_N;
    const float* r1 = r0 + W_N;

    float res[4];
    #pragma unroll
    for (int q = 0; q < 4; ++q) {
        int ox = oxq * 4 + q;
        float sxf = (float)ox * (107.0f / 255.0f);
        int x0 = (int)sxf; x0 = min(x0, W_N - 2);
        float wx = sxf - (float)x0;
        float c0 = r0[x0]     * (1.0f - wy) + r1[x0]     * wy;
        float c1 = r0[x0 + 1] * (1.0f - wy) + r1[x0 + 1] * wy;
        res[q] = c0 * (1.0f - wx) + c1 * wx;
    }
    *reinterpret_cast<float4*>(out + (size_t)idx * 4) =
        make_float4(res[0], res[1], res[2], res[3]);
}

// ---------------------------------------------------------------------------
extern "C" void kernel_launch(void* const* d_in, const int* in_sizes, int n_in,
                              void* d_out, int out_size, void* d_ws, size_t ws_size,
                              hipStream_t stream)
{
    (void)in_sizes; (void)n_in; (void)out_size; (void)ws_size;
    const float* x    = (const float*)d_in[0];
    const float* rel  = (const float*)d_in[1];
    const int*   adj  = (const int*)d_in[2];
    const float* cmsk = (const float*)d_in[3];
    const float* wcls = (const float*)d_in[4];
    const float* bcls = (const float*)d_in[5];
    float* out = (float*)d_out;   // reference output dtype is float32

    float* ws    = (float*)d_ws;
    float* part  = ws;                          // 2*8*7*8640 = 967,680 f32
    float* z     = part  + GSP * A_N * O_N * P_N;
    float* ssolo = z     + A_N * O_N * P_N;
    float* saggr = ssolo + A_N * O_N * P_N;     // total ~9.7 MB

    k_convp   <<<A_N * NTIL * GSP, TILE, 0, stream>>>(x, wcls, part);
    k_finalize<<<270, 256, 0, stream>>>(part, cmsk, wcls, bcls, z, ssolo);
    k_aggr    <<<1080, 64, 0, stream>>>(z, rel, adj, bcls, saggr);
    k_upsample<<<7168, 256, 0, stream>>>(ssolo, saggr, out);
}